// Round 1
// baseline (976.539 us; speedup 1.0000x reference)
//
#include <hip/hip_runtime.h>
#include <math.h>

#define Bc 8
#define Nc 128
#define Dc 256
#define Hc 8
#define DKc 32

// ---------------------------------------------------------------------------
// Generic tiled GEMM: C[M,256] = X[M,256] @ W[256,256]^T + bias
// 64x64 tile per block, BK=16, 256 threads, 4x4 micro-tile per thread.
// M must be a multiple of 64 (true for all call sites: 1024 or 131072).
// ---------------------------------------------------------------------------
__global__ __launch_bounds__(256) void gemm_xwT_kernel(
    const float* __restrict__ X, const float* __restrict__ W,
    const float* __restrict__ bias, float* __restrict__ C, int M) {
  __shared__ float As[64][17];
  __shared__ float Ws[64][17];
  const int t = threadIdx.x;
  const int tx = t & 15;
  const int ty = t >> 4;
  const size_t row0 = (size_t)blockIdx.y * 64;
  const int col0 = blockIdx.x * 64;
  const int lr = t >> 2;          // 0..63
  const int lc = (t & 3) * 4;     // 0,4,8,12

  float acc[4][4] = {};

  for (int kk = 0; kk < 256; kk += 16) {
    float4 av = *(const float4*)&X[(row0 + lr) * 256 + kk + lc];
    float4 wv = *(const float4*)&W[(size_t)(col0 + lr) * 256 + kk + lc];
    As[lr][lc] = av.x; As[lr][lc + 1] = av.y; As[lr][lc + 2] = av.z; As[lr][lc + 3] = av.w;
    Ws[lr][lc] = wv.x; Ws[lr][lc + 1] = wv.y; Ws[lr][lc + 2] = wv.z; Ws[lr][lc + 3] = wv.w;
    __syncthreads();
#pragma unroll
    for (int e = 0; e < 16; ++e) {
      float a[4], w[4];
#pragma unroll
      for (int r = 0; r < 4; ++r) a[r] = As[ty * 4 + r][e];
#pragma unroll
      for (int c = 0; c < 4; ++c) w[c] = Ws[tx * 4 + c][e];
#pragma unroll
      for (int r = 0; r < 4; ++r)
#pragma unroll
        for (int c = 0; c < 4; ++c) acc[r][c] = fmaf(a[r], w[c], acc[r][c]);
    }
    __syncthreads();
  }

  const float4 bv = *(const float4*)&bias[col0 + tx * 4];
#pragma unroll
  for (int r = 0; r < 4; ++r) {
    float4 o;
    o.x = acc[r][0] + bv.x;
    o.y = acc[r][1] + bv.y;
    o.z = acc[r][2] + bv.z;
    o.w = acc[r][3] + bv.w;
    *(float4*)&C[(row0 + ty * 4 + r) * 256 + col0 + tx * 4] = o;
  }
}

// ---------------------------------------------------------------------------
// adjacency softmax: adjs[b,i,j] = softmax_j( mask[b,j] ? -lam*adj[b,i,j] : -inf )
// one block (128 threads) per (b,i) row.
// ---------------------------------------------------------------------------
__global__ __launch_bounds__(128) void adj_softmax_kernel(
    const float* __restrict__ adj, const int* __restrict__ mask,
    const float* __restrict__ lam_p, float* __restrict__ adjs) {
  __shared__ float red[128];
  const int bi = blockIdx.x;       // b*128 + i
  const int b = bi >> 7;
  const int j = threadIdx.x;
  const float lam = lam_p[0];
  float x = (mask[b * 128 + j] != 0) ? (-lam * adj[(size_t)bi * 128 + j]) : -INFINITY;
  red[j] = x; __syncthreads();
  for (int s = 64; s > 0; s >>= 1) { if (j < s) red[j] = fmaxf(red[j], red[j + s]); __syncthreads(); }
  const float mx = red[0]; __syncthreads();
  const float e = expf(x - mx);
  red[j] = e; __syncthreads();
  for (int s = 64; s > 0; s >>= 1) { if (j < s) red[j] += red[j + s]; __syncthreads(); }
  const float z = red[0];
  adjs[(size_t)bi * 128 + j] = e / z;
}

// ---------------------------------------------------------------------------
// scores: for fixed (b,m), over all n,h:
//   osc[b,h,m,n] = q[b,m,h]·k[b,m,n,h] / sqrt(DK)
//   isc[b,h,n,m] = q[b,n,h]·k[b,m,n,h] / sqrt(DK)
// one block (4 waves) per (b,m); each wave handles n stepping by 4.
// per-lane float4 of the k row; 8-lane group = one head (8*4 = 32 = DK).
// ---------------------------------------------------------------------------
__global__ __launch_bounds__(256) void scores_kernel(
    const float* __restrict__ kbuf, const float* __restrict__ q,
    float* __restrict__ osc, float* __restrict__ isc) {
  const int bm = blockIdx.x;            // b*128 + m
  const int b = bm >> 7;
  const int m = bm & 127;
  const int lane = threadIdx.x & 63;
  const int wave = threadIdx.x >> 6;
  const float inv_sqrt = 0.17677669529663687f;  // 1/sqrt(32)

  const float4 qm = *(const float4*)&q[((size_t)b * 128 + m) * 256 + lane * 4];

  for (int n = wave; n < 128; n += 4) {
    const float4 kr = *(const float4*)&kbuf[((size_t)bm * 128 + n) * 256 + lane * 4];
    const float4 qn = *(const float4*)&q[((size_t)b * 128 + n) * 256 + lane * 4];
    float po = kr.x * qm.x + kr.y * qm.y + kr.z * qm.z + kr.w * qm.w;
    float pi = kr.x * qn.x + kr.y * qn.y + kr.z * qn.z + kr.w * qn.w;
#pragma unroll
    for (int off = 1; off < 8; off <<= 1) {
      po += __shfl_xor(po, off, 64);
      pi += __shfl_xor(pi, off, 64);
    }
    if ((lane & 7) == 0) {
      const int h = lane >> 3;
      osc[(((size_t)(b * 8 + h) * 128 + m) * 128) + n] = po * inv_sqrt;
      isc[(((size_t)(b * 8 + h) * 128 + n) * 128) + m] = pi * inv_sqrt;
    }
  }
}

// ---------------------------------------------------------------------------
// message: msg[b,h,i,j] = (softmax_j osc_row + softmax_j isc_row
//                          - (i==j)*softmax_j osc_row) * adjs[b,i,j]
// one block (128 threads) per (b,h,i) row.
// ---------------------------------------------------------------------------
__global__ __launch_bounds__(128) void message_kernel(
    const float* __restrict__ osc, const float* __restrict__ isc,
    const float* __restrict__ adjs, const int* __restrict__ mask,
    float* __restrict__ msg) {
  __shared__ float red[128];
  const int bhi = blockIdx.x;          // (b*8+h)*128 + i
  const int i = bhi & 127;
  const int b = bhi >> 10;             // /(8*128)
  const int j = threadIdx.x;
  const bool mj = mask[b * 128 + j] != 0;

  const float so = mj ? osc[(size_t)bhi * 128 + j] : -INFINITY;
  const float si = mj ? isc[(size_t)bhi * 128 + j] : -INFINITY;

  // softmax(out)
  red[j] = so; __syncthreads();
  for (int s = 64; s > 0; s >>= 1) { if (j < s) red[j] = fmaxf(red[j], red[j + s]); __syncthreads(); }
  const float mo = red[0]; __syncthreads();
  const float eo = expf(so - mo);
  red[j] = eo; __syncthreads();
  for (int s = 64; s > 0; s >>= 1) { if (j < s) red[j] += red[j + s]; __syncthreads(); }
  const float zo = red[0]; __syncthreads();
  const float oa = eo / zo;

  // softmax(in)
  red[j] = si; __syncthreads();
  for (int s = 64; s > 0; s >>= 1) { if (j < s) red[j] = fmaxf(red[j], red[j + s]); __syncthreads(); }
  const float mi = red[0]; __syncthreads();
  const float ei = expf(si - mi);
  red[j] = ei; __syncthreads();
  for (int s = 64; s > 0; s >>= 1) { if (j < s) red[j] += red[j + s]; __syncthreads(); }
  const float zi = red[0];
  const float ia = ei / zi;

  float val = oa + ia - ((i == j) ? oa : 0.0f);
  val *= adjs[((size_t)(b * 128 + i)) * 128 + j];
  msg[(size_t)bhi * 128 + j] = val;
}

// ---------------------------------------------------------------------------
// node_hidden[b,m,h*32+dk] = sum_n msg[b,h,m,n] * v[b,n,h*32+dk]
// one block per (b,h,mblk); mblk covers 32 m rows.
// ---------------------------------------------------------------------------
__global__ __launch_bounds__(256) void node_hidden_kernel(
    const float* __restrict__ msg, const float* __restrict__ v,
    float* __restrict__ nh) {
  __shared__ float Ms[32][129];
  __shared__ float Vs[128][33];
  const int blk = blockIdx.x;          // (b*8+h)*4 + mblk
  const int mblk = blk & 3;
  const int bh = blk >> 2;
  const int h = bh & 7;
  const int b = bh >> 3;
  const int t = threadIdx.x;

  {
    const int n = t & 127, r0 = t >> 7;  // 2 rows per pass
#pragma unroll
    for (int p = 0; p < 16; ++p) {
      const int r = r0 + p * 2;
      Ms[r][n] = msg[((size_t)bh * 128 + mblk * 32 + r) * 128 + n];
    }
  }
  {
    const int dk = t & 31, n0 = t >> 5;  // 8 rows per pass
#pragma unroll
    for (int p = 0; p < 16; ++p) {
      const int n = n0 + p * 8;
      Vs[n][dk] = v[((size_t)b * 128 + n) * 256 + h * 32 + dk];
    }
  }
  __syncthreads();

  const int dk = t & 31;
  const int mg = t >> 5;               // 0..7
  float acc[4] = {0.f, 0.f, 0.f, 0.f};
  for (int n = 0; n < 128; ++n) {
    const float vv = Vs[n][dk];
#pragma unroll
    for (int r = 0; r < 4; ++r) acc[r] = fmaf(Ms[mg + 8 * r][n], vv, acc[r]);
  }
#pragma unroll
  for (int r = 0; r < 4; ++r) {
    const int m = mblk * 32 + mg + 8 * r;
    nh[((size_t)b * 128 + m) * 256 + h * 32 + dk] = acc[r];
  }
}

// ---------------------------------------------------------------------------
// edge out, IN PLACE on kbuf (= edge region of d_out):
//   out[b,m,n,d'] = sum_d Weo[d',d] * msg[b, d/32, m, n] * k[b,m,n,d] + beo[d']
// one block owns 64 rows (b,m,nblk) and ALL 256 output cols -> no cross-block
// read/write hazard for the in-place update.
// ---------------------------------------------------------------------------
__global__ __launch_bounds__(256) void edge_out_kernel(
    float* __restrict__ kio, const float* __restrict__ msg,
    const float* __restrict__ Weo, const float* __restrict__ beo) {
  __shared__ float As[64][17];
  __shared__ float Ws[256][17];
  __shared__ float Msgs[64][8];
  const int blk = blockIdx.x;          // (b*128+m)*2 + nblk
  const int nblk = blk & 1;
  const int bm = blk >> 1;
  const int b = bm >> 7;
  const int m = bm & 127;
  const int n0 = nblk * 64;
  const int t = threadIdx.x;
  const int tx = t & 15;
  const int ty = t >> 4;
  const int lr = t >> 2;               // 0..63
  const int lc = (t & 3) * 4;          // 0,4,8,12

  // stage msg for these 64 rows, all 8 heads
#pragma unroll
  for (int p = 0; p < 2; ++p) {
    const int idx = t + p * 256;
    const int r = idx >> 3, h = idx & 7;
    Msgs[r][h] = msg[(((size_t)(b * 8 + h) * 128 + m) * 128) + n0 + r];
  }
  __syncthreads();

  const size_t rowbase = ((size_t)bm * 128 + n0) * 256;
  float acc[4][16] = {};

  for (int kk = 0; kk < 256; kk += 16) {
    // stage A (k row scaled by per-head msg)
    {
      const float4 av = *(const float4*)&kio[rowbase + (size_t)lr * 256 + kk + lc];
      const float sc = Msgs[lr][(kk + lc) >> 5];   // 4 cols stay in one head
      As[lr][lc] = av.x * sc; As[lr][lc + 1] = av.y * sc;
      As[lr][lc + 2] = av.z * sc; As[lr][lc + 3] = av.w * sc;
    }
    // stage full-width Weo chunk: 256 rows x 16 cols
#pragma unroll
    for (int p = 0; p < 4; ++p) {
      const int jrow = lr + p * 64;
      const float4 wv = *(const float4*)&Weo[(size_t)jrow * 256 + kk + lc];
      Ws[jrow][lc] = wv.x; Ws[jrow][lc + 1] = wv.y;
      Ws[jrow][lc + 2] = wv.z; Ws[jrow][lc + 3] = wv.w;
    }
    __syncthreads();
#pragma unroll
    for (int e = 0; e < 16; ++e) {
      float a[4];
#pragma unroll
      for (int r = 0; r < 4; ++r) a[r] = As[ty * 4 + r][e];
#pragma unroll
      for (int ch = 0; ch < 4; ++ch) {
        float w[4];
#pragma unroll
        for (int c = 0; c < 4; ++c) w[c] = Ws[ch * 64 + tx * 4 + c][e];
#pragma unroll
        for (int r = 0; r < 4; ++r)
#pragma unroll
          for (int c = 0; c < 4; ++c)
            acc[r][ch * 4 + c] = fmaf(a[r], w[c], acc[r][ch * 4 + c]);
      }
    }
    __syncthreads();
  }

  // in-place write: only this block touches these 64 rows
#pragma unroll
  for (int ch = 0; ch < 4; ++ch) {
    const float4 bv = *(const float4*)&beo[ch * 64 + tx * 4];
#pragma unroll
    for (int r = 0; r < 4; ++r) {
      float4 o;
      o.x = acc[r][ch * 4 + 0] + bv.x;
      o.y = acc[r][ch * 4 + 1] + bv.y;
      o.z = acc[r][ch * 4 + 2] + bv.z;
      o.w = acc[r][ch * 4 + 3] + bv.w;
      *(float4*)&kio[rowbase + (size_t)(ty * 4 + r) * 256 + ch * 64 + tx * 4] = o;
    }
  }
}

// ---------------------------------------------------------------------------
extern "C" void kernel_launch(void* const* d_in, const int* in_sizes, int n_in,
                              void* d_out, int out_size, void* d_ws, size_t ws_size,
                              hipStream_t stream) {
  (void)in_sizes; (void)n_in; (void)out_size; (void)ws_size;
  const float* query_node = (const float*)d_in[0];
  const float* value_node = (const float*)d_in[1];
  const float* key_edge   = (const float*)d_in[2];
  const float* adj_matrix = (const float*)d_in[3];
  const int*   mask       = (const int*)d_in[4];
  const float* Wq  = (const float*)d_in[5];
  const float* bq  = (const float*)d_in[6];
  const float* Wk  = (const float*)d_in[7];
  const float* bk  = (const float*)d_in[8];
  const float* Wv  = (const float*)d_in[9];
  const float* bv  = (const float*)d_in[10];
  const float* Wno = (const float*)d_in[11];
  const float* bno = (const float*)d_in[12];
  const float* Weo = (const float*)d_in[13];
  const float* beo = (const float*)d_in[14];
  const float* lam = (const float*)d_in[15];

  float* out = (float*)d_out;
  float* node_out = out;                                  // [B,N,D]
  float* kbuf = out + (size_t)Bc * Nc * Dc;               // edge region doubles as k scratch

  float* ws = (float*)d_ws;
  float* q    = ws; ws += (size_t)Bc * Nc * Dc;           // 262144
  float* v    = ws; ws += (size_t)Bc * Nc * Dc;           // 262144
  float* adjs = ws; ws += (size_t)Bc * Nc * Nc;           // 131072
  float* osc  = ws; ws += (size_t)Bc * Hc * Nc * Nc;      // 1048576
  float* isc  = ws; ws += (size_t)Bc * Hc * Nc * Nc;      // 1048576
  float* msg  = ws; ws += (size_t)Bc * Hc * Nc * Nc;      // 1048576
  float* nh   = ws; ws += (size_t)Bc * Nc * Dc;           // 262144

  // q, v projections
  gemm_xwT_kernel<<<dim3(4, 16), 256, 0, stream>>>(query_node, Wq, bq, q, Bc * Nc);
  gemm_xwT_kernel<<<dim3(4, 16), 256, 0, stream>>>(value_node, Wv, bv, v, Bc * Nc);
  // big k projection: [131072,256] @ Wk^T  -> kbuf (edge region of d_out)
  gemm_xwT_kernel<<<dim3(4, 2048), 256, 0, stream>>>(key_edge, Wk, bk, kbuf, Bc * Nc * Nc);
  // adjacency softmax
  adj_softmax_kernel<<<dim3(Bc * Nc), 128, 0, stream>>>(adj_matrix, mask, lam, adjs);
  // attention scores (out + in)
  scores_kernel<<<dim3(Bc * Nc), 256, 0, stream>>>(kbuf, q, osc, isc);
  // softmaxes + message
  message_kernel<<<dim3(Bc * Hc * Nc), 128, 0, stream>>>(osc, isc, adjs, mask, msg);
  // node hidden + node projection
  node_hidden_kernel<<<dim3(Bc * Hc * 4), 256, 0, stream>>>(msg, v, nh);
  gemm_xwT_kernel<<<dim3(4, 16), 256, 0, stream>>>(nh, Wno, bno, node_out, Bc * Nc);
  // edge output, in place over kbuf
  edge_out_kernel<<<dim3(Bc * Nc * 2), 256, 0, stream>>>(kbuf, msg, Weo, beo);
}

// Round 2
// 735.061 us; speedup vs baseline: 1.3285x; 1.3285x over previous
//
#include <hip/hip_runtime.h>
#include <math.h>

#define Bc 8
#define Nc 128
#define Dc 256
#define Hc 8
#define DKc 32

// ---------------------------------------------------------------------------
// Small GEMM: C[M,256] = X[M,256] @ W[256,256]^T + bias  (M = 1024 call sites)
// 64x64 tile, BK=16, 256 threads, 4x4 micro-tile. (unchanged from R1)
// ---------------------------------------------------------------------------
__global__ __launch_bounds__(256) void gemm_xwT_kernel(
    const float* __restrict__ X, const float* __restrict__ W,
    const float* __restrict__ bias, float* __restrict__ C, int M) {
  __shared__ float As[64][17];
  __shared__ float Ws[64][17];
  const int t = threadIdx.x;
  const int tx = t & 15;
  const int ty = t >> 4;
  const size_t row0 = (size_t)blockIdx.y * 64;
  const int col0 = blockIdx.x * 64;
  const int lr = t >> 2;          // 0..63
  const int lc = (t & 3) * 4;     // 0,4,8,12

  float acc[4][4] = {};

  for (int kk = 0; kk < 256; kk += 16) {
    float4 av = *(const float4*)&X[(row0 + lr) * 256 + kk + lc];
    float4 wv = *(const float4*)&W[(size_t)(col0 + lr) * 256 + kk + lc];
    As[lr][lc] = av.x; As[lr][lc + 1] = av.y; As[lr][lc + 2] = av.z; As[lr][lc + 3] = av.w;
    Ws[lr][lc] = wv.x; Ws[lr][lc + 1] = wv.y; Ws[lr][lc + 2] = wv.z; Ws[lr][lc + 3] = wv.w;
    __syncthreads();
#pragma unroll
    for (int e = 0; e < 16; ++e) {
      float a[4], w[4];
#pragma unroll
      for (int r = 0; r < 4; ++r) a[r] = As[ty * 4 + r][e];
#pragma unroll
      for (int c = 0; c < 4; ++c) w[c] = Ws[tx * 4 + c][e];
#pragma unroll
      for (int r = 0; r < 4; ++r)
#pragma unroll
        for (int c = 0; c < 4; ++c) acc[r][c] = fmaf(a[r], w[c], acc[r][c]);
    }
    __syncthreads();
  }

  const float4 bv = *(const float4*)&bias[col0 + tx * 4];
#pragma unroll
  for (int r = 0; r < 4; ++r) {
    float4 o;
    o.x = acc[r][0] + bv.x;
    o.y = acc[r][1] + bv.y;
    o.z = acc[r][2] + bv.z;
    o.w = acc[r][3] + bv.w;
    *(float4*)&C[(row0 + ty * 4 + r) * 256 + col0 + tx * 4] = o;
  }
}

// ---------------------------------------------------------------------------
// Big GEMM: C[M,256] = X[M,256] @ W[256,256]^T + bias, M multiple of 128.
// 128x128 tile, BK=16, 256 threads, 8x8 micro-tile (split 4+4, 64 apart).
// K-major LDS tiles so fragment reads are ds_read_b128.
//   As[e][i] = X[row0+i][kk+e], Ws[e][j] = W[col0+j][kk+e], pad 132 (=4 mod 32
//   bank stride -> 2-way write aliasing = free).
// ---------------------------------------------------------------------------
__global__ __launch_bounds__(256) void gemm128_kernel(
    const float* __restrict__ X, const float* __restrict__ W,
    const float* __restrict__ bias, float* __restrict__ C, int M) {
  __shared__ float As[16][132];
  __shared__ float Ws[16][132];
  const int t = threadIdx.x;
  const int tx = t & 15;         // col group
  const int ty = t >> 4;         // row group
  const size_t row0 = (size_t)blockIdx.y * 128;
  const int col0 = blockIdx.x * 128;

  // staging: 2 float4 per matrix per thread; l in [0,512): row=l>>2, c=(l&3)*4
  const int r0g = t >> 2, c0g = (t & 3) * 4;
  const int r1g = r0g + 64;      // (t+256)>>2

  float acc[8][8] = {};

  for (int kk = 0; kk < 256; kk += 16) {
    const float4 a0 = *(const float4*)&X[(row0 + r0g) * 256 + kk + c0g];
    const float4 a1 = *(const float4*)&X[(row0 + r1g) * 256 + kk + c0g];
    const float4 w0 = *(const float4*)&W[(size_t)(col0 + r0g) * 256 + kk + c0g];
    const float4 w1 = *(const float4*)&W[(size_t)(col0 + r1g) * 256 + kk + c0g];
    __syncthreads();   // previous iteration's compute done
    As[c0g + 0][r0g] = a0.x; As[c0g + 1][r0g] = a0.y; As[c0g + 2][r0g] = a0.z; As[c0g + 3][r0g] = a0.w;
    As[c0g + 0][r1g] = a1.x; As[c0g + 1][r1g] = a1.y; As[c0g + 2][r1g] = a1.z; As[c0g + 3][r1g] = a1.w;
    Ws[c0g + 0][r0g] = w0.x; Ws[c0g + 1][r0g] = w0.y; Ws[c0g + 2][r0g] = w0.z; Ws[c0g + 3][r0g] = w0.w;
    Ws[c0g + 0][r1g] = w1.x; Ws[c0g + 1][r1g] = w1.y; Ws[c0g + 2][r1g] = w1.z; Ws[c0g + 3][r1g] = w1.w;
    __syncthreads();
#pragma unroll
    for (int e = 0; e < 16; ++e) {
      const float4 aLo = *(const float4*)&As[e][ty * 4];
      const float4 aHi = *(const float4*)&As[e][64 + ty * 4];
      const float4 wLo = *(const float4*)&Ws[e][tx * 4];
      const float4 wHi = *(const float4*)&Ws[e][64 + tx * 4];
      const float ar[8] = {aLo.x, aLo.y, aLo.z, aLo.w, aHi.x, aHi.y, aHi.z, aHi.w};
      const float wr[8] = {wLo.x, wLo.y, wLo.z, wLo.w, wHi.x, wHi.y, wHi.z, wHi.w};
#pragma unroll
      for (int r = 0; r < 8; ++r)
#pragma unroll
        for (int c = 0; c < 8; ++c) acc[r][c] = fmaf(ar[r], wr[c], acc[r][c]);
    }
  }

  const float4 bv0 = *(const float4*)&bias[col0 + tx * 4];
  const float4 bv1 = *(const float4*)&bias[col0 + 64 + tx * 4];
#pragma unroll
  for (int r = 0; r < 8; ++r) {
    const size_t row = row0 + (r < 4 ? ty * 4 + r : 64 + ty * 4 + (r - 4));
    float4 o0, o1;
    o0.x = acc[r][0] + bv0.x; o0.y = acc[r][1] + bv0.y;
    o0.z = acc[r][2] + bv0.z; o0.w = acc[r][3] + bv0.w;
    o1.x = acc[r][4] + bv1.x; o1.y = acc[r][5] + bv1.y;
    o1.z = acc[r][6] + bv1.z; o1.w = acc[r][7] + bv1.w;
    *(float4*)&C[row * 256 + col0 + tx * 4] = o0;
    *(float4*)&C[row * 256 + col0 + 64 + tx * 4] = o1;
  }
}

// ---------------------------------------------------------------------------
// adjacency softmax (unchanged)
// ---------------------------------------------------------------------------
__global__ __launch_bounds__(128) void adj_softmax_kernel(
    const float* __restrict__ adj, const int* __restrict__ mask,
    const float* __restrict__ lam_p, float* __restrict__ adjs) {
  __shared__ float red[128];
  const int bi = blockIdx.x;
  const int b = bi >> 7;
  const int j = threadIdx.x;
  const float lam = lam_p[0];
  float x = (mask[b * 128 + j] != 0) ? (-lam * adj[(size_t)bi * 128 + j]) : -INFINITY;
  red[j] = x; __syncthreads();
  for (int s = 64; s > 0; s >>= 1) { if (j < s) red[j] = fmaxf(red[j], red[j + s]); __syncthreads(); }
  const float mx = red[0]; __syncthreads();
  const float e = expf(x - mx);
  red[j] = e; __syncthreads();
  for (int s = 64; s > 0; s >>= 1) { if (j < s) red[j] += red[j + s]; __syncthreads(); }
  const float z = red[0];
  adjs[(size_t)bi * 128 + j] = e / z;
}

// ---------------------------------------------------------------------------
// scores (unchanged)
// ---------------------------------------------------------------------------
__global__ __launch_bounds__(256) void scores_kernel(
    const float* __restrict__ kbuf, const float* __restrict__ q,
    float* __restrict__ osc, float* __restrict__ isc) {
  const int bm = blockIdx.x;
  const int b = bm >> 7;
  const int m = bm & 127;
  const int lane = threadIdx.x & 63;
  const int wave = threadIdx.x >> 6;
  const float inv_sqrt = 0.17677669529663687f;

  const float4 qm = *(const float4*)&q[((size_t)b * 128 + m) * 256 + lane * 4];

  for (int n = wave; n < 128; n += 4) {
    const float4 kr = *(const float4*)&kbuf[((size_t)bm * 128 + n) * 256 + lane * 4];
    const float4 qn = *(const float4*)&q[((size_t)b * 128 + n) * 256 + lane * 4];
    float po = kr.x * qm.x + kr.y * qm.y + kr.z * qm.z + kr.w * qm.w;
    float pi = kr.x * qn.x + kr.y * qn.y + kr.z * qn.z + kr.w * qn.w;
#pragma unroll
    for (int off = 1; off < 8; off <<= 1) {
      po += __shfl_xor(po, off, 64);
      pi += __shfl_xor(pi, off, 64);
    }
    if ((lane & 7) == 0) {
      const int h = lane >> 3;
      osc[(((size_t)(b * 8 + h) * 128 + m) * 128) + n] = po * inv_sqrt;
      isc[(((size_t)(b * 8 + h) * 128 + n) * 128) + m] = pi * inv_sqrt;
    }
  }
}

// ---------------------------------------------------------------------------
// message (unchanged)
// ---------------------------------------------------------------------------
__global__ __launch_bounds__(128) void message_kernel(
    const float* __restrict__ osc, const float* __restrict__ isc,
    const float* __restrict__ adjs, const int* __restrict__ mask,
    float* __restrict__ msg) {
  __shared__ float red[128];
  const int bhi = blockIdx.x;
  const int i = bhi & 127;
  const int b = bhi >> 10;
  const int j = threadIdx.x;
  const bool mj = mask[b * 128 + j] != 0;

  const float so = mj ? osc[(size_t)bhi * 128 + j] : -INFINITY;
  const float si = mj ? isc[(size_t)bhi * 128 + j] : -INFINITY;

  red[j] = so; __syncthreads();
  for (int s = 64; s > 0; s >>= 1) { if (j < s) red[j] = fmaxf(red[j], red[j + s]); __syncthreads(); }
  const float mo = red[0]; __syncthreads();
  const float eo = expf(so - mo);
  red[j] = eo; __syncthreads();
  for (int s = 64; s > 0; s >>= 1) { if (j < s) red[j] += red[j + s]; __syncthreads(); }
  const float zo = red[0]; __syncthreads();
  const float oa = eo / zo;

  red[j] = si; __syncthreads();
  for (int s = 64; s > 0; s >>= 1) { if (j < s) red[j] = fmaxf(red[j], red[j + s]); __syncthreads(); }
  const float mi = red[0]; __syncthreads();
  const float ei = expf(si - mi);
  red[j] = ei; __syncthreads();
  for (int s = 64; s > 0; s >>= 1) { if (j < s) red[j] += red[j + s]; __syncthreads(); }
  const float zi = red[0];
  const float ia = ei / zi;

  float val = oa + ia - ((i == j) ? oa : 0.0f);
  val *= adjs[((size_t)(b * 128 + i)) * 128 + j];
  msg[(size_t)bhi * 128 + j] = val;
}

// ---------------------------------------------------------------------------
// node_hidden (unchanged)
// ---------------------------------------------------------------------------
__global__ __launch_bounds__(256) void node_hidden_kernel(
    const float* __restrict__ msg, const float* __restrict__ v,
    float* __restrict__ nh) {
  __shared__ float Ms[32][129];
  __shared__ float Vs[128][33];
  const int blk = blockIdx.x;
  const int mblk = blk & 3;
  const int bh = blk >> 2;
  const int h = bh & 7;
  const int b = bh >> 3;
  const int t = threadIdx.x;

  {
    const int n = t & 127, r0 = t >> 7;
#pragma unroll
    for (int p = 0; p < 16; ++p) {
      const int r = r0 + p * 2;
      Ms[r][n] = msg[((size_t)bh * 128 + mblk * 32 + r) * 128 + n];
    }
  }
  {
    const int dk = t & 31, n0 = t >> 5;
#pragma unroll
    for (int p = 0; p < 16; ++p) {
      const int n = n0 + p * 8;
      Vs[n][dk] = v[((size_t)b * 128 + n) * 256 + h * 32 + dk];
    }
  }
  __syncthreads();

  const int dk = t & 31;
  const int mg = t >> 5;
  float acc[4] = {0.f, 0.f, 0.f, 0.f};
  for (int n = 0; n < 128; ++n) {
    const float vv = Vs[n][dk];
#pragma unroll
    for (int r = 0; r < 4; ++r) acc[r] = fmaf(Ms[mg + 8 * r][n], vv, acc[r]);
  }
#pragma unroll
  for (int r = 0; r < 4; ++r) {
    const int m = mblk * 32 + mg + 8 * r;
    nh[((size_t)b * 128 + m) * 256 + h * 32 + dk] = acc[r];
  }
}

// ---------------------------------------------------------------------------
// edge out, IN PLACE on kbuf. K-major LDS, ds_read_b128 fragments.
// One block owns 64 rows x all 256 cols -> no cross-block in-place hazard.
//   As[e][i] = msg_scale * k[row i][kk+e]  (pad 68)
//   Ws[e][j] = Weo[j][kk+e]                (pad 260)
// ---------------------------------------------------------------------------
__global__ __launch_bounds__(256) void edge_out_kernel(
    float* __restrict__ kio, const float* __restrict__ msg,
    const float* __restrict__ Weo, const float* __restrict__ beo) {
  __shared__ float As[16][68];
  __shared__ float Ws[16][260];
  __shared__ float Msgs[64][9];
  const int blk = blockIdx.x;          // (b*128+m)*2 + nblk
  const int nblk = blk & 1;
  const int bm = blk >> 1;
  const int b = bm >> 7;
  const int m = bm & 127;
  const int n0 = nblk * 64;
  const int t = threadIdx.x;
  const int tx = t & 15;               // col group (16 cols via 4 chunks)
  const int ty = t >> 4;               // row group (4 rows)

  // stage msg for these 64 rows, all 8 heads
#pragma unroll
  for (int p = 0; p < 2; ++p) {
    const int idx = t + p * 256;
    const int r = idx >> 3, h = idx & 7;
    Msgs[r][h] = msg[(((size_t)(b * 8 + h) * 128 + m) * 128) + n0 + r];
  }
  __syncthreads();

  const size_t rowbase = ((size_t)bm * 128 + n0) * 256;
  // staging indices
  const int ar = t >> 2;               // 0..63  (A rows)
  const int ac = (t & 3) * 4;          // 0,4,8,12 (K cols)
  float acc[4][16] = {};

  for (int kk = 0; kk < 256; kk += 16) {
    const float4 kv = *(const float4*)&kio[rowbase + (size_t)ar * 256 + kk + ac];
    float4 wv[4];
#pragma unroll
    for (int p = 0; p < 4; ++p) {
      const int j = ar + p * 64;       // 0..255 (Weo rows = output cols)
      wv[p] = *(const float4*)&Weo[(size_t)j * 256 + kk + ac];
    }
    const float sc = Msgs[ar][(kk + ac) >> 5];   // 4 K-cols stay in one head
    __syncthreads();   // previous compute done
    As[ac + 0][ar] = kv.x * sc; As[ac + 1][ar] = kv.y * sc;
    As[ac + 2][ar] = kv.z * sc; As[ac + 3][ar] = kv.w * sc;
#pragma unroll
    for (int p = 0; p < 4; ++p) {
      const int j = ar + p * 64;
      Ws[ac + 0][j] = wv[p].x; Ws[ac + 1][j] = wv[p].y;
      Ws[ac + 2][j] = wv[p].z; Ws[ac + 3][j] = wv[p].w;
    }
    __syncthreads();
#pragma unroll
    for (int e = 0; e < 16; ++e) {
      const float4 av = *(const float4*)&As[e][ty * 4];
      const float a[4] = {av.x, av.y, av.z, av.w};
#pragma unroll
      for (int ch = 0; ch < 4; ++ch) {
        const float4 wf = *(const float4*)&Ws[e][ch * 64 + tx * 4];
        const float w[4] = {wf.x, wf.y, wf.z, wf.w};
#pragma unroll
        for (int r = 0; r < 4; ++r)
#pragma unroll
          for (int c = 0; c < 4; ++c)
            acc[r][ch * 4 + c] = fmaf(a[r], w[c], acc[r][ch * 4 + c]);
      }
    }
  }

  // in-place write: only this block touches these 64 rows
#pragma unroll
  for (int ch = 0; ch < 4; ++ch) {
    const float4 bv = *(const float4*)&beo[ch * 64 + tx * 4];
#pragma unroll
    for (int r = 0; r < 4; ++r) {
      float4 o;
      o.x = acc[r][ch * 4 + 0] + bv.x;
      o.y = acc[r][ch * 4 + 1] + bv.y;
      o.z = acc[r][ch * 4 + 2] + bv.z;
      o.w = acc[r][ch * 4 + 3] + bv.w;
      *(float4*)&kio[rowbase + (size_t)(ty * 4 + r) * 256 + ch * 64 + tx * 4] = o;
    }
  }
}

// ---------------------------------------------------------------------------
extern "C" void kernel_launch(void* const* d_in, const int* in_sizes, int n_in,
                              void* d_out, int out_size, void* d_ws, size_t ws_size,
                              hipStream_t stream) {
  (void)in_sizes; (void)n_in; (void)out_size; (void)ws_size;
  const float* query_node = (const float*)d_in[0];
  const float* value_node = (const float*)d_in[1];
  const float* key_edge   = (const float*)d_in[2];
  const float* adj_matrix = (const float*)d_in[3];
  const int*   mask       = (const int*)d_in[4];
  const float* Wq  = (const float*)d_in[5];
  const float* bq  = (const float*)d_in[6];
  const float* Wk  = (const float*)d_in[7];
  const float* bk  = (const float*)d_in[8];
  const float* Wv  = (const float*)d_in[9];
  const float* bv  = (const float*)d_in[10];
  const float* Wno = (const float*)d_in[11];
  const float* bno = (const float*)d_in[12];
  const float* Weo = (const float*)d_in[13];
  const float* beo = (const float*)d_in[14];
  const float* lam = (const float*)d_in[15];

  float* out = (float*)d_out;
  float* node_out = out;                                  // [B,N,D]
  float* kbuf = out + (size_t)Bc * Nc * Dc;               // edge region doubles as k scratch

  float* ws = (float*)d_ws;
  float* q    = ws; ws += (size_t)Bc * Nc * Dc;
  float* v    = ws; ws += (size_t)Bc * Nc * Dc;
  float* adjs = ws; ws += (size_t)Bc * Nc * Nc;
  float* osc  = ws; ws += (size_t)Bc * Hc * Nc * Nc;
  float* isc  = ws; ws += (size_t)Bc * Hc * Nc * Nc;
  float* msg  = ws; ws += (size_t)Bc * Hc * Nc * Nc;
  float* nh   = ws; ws += (size_t)Bc * Nc * Dc;

  // q, v projections (small)
  gemm_xwT_kernel<<<dim3(4, 16), 256, 0, stream>>>(query_node, Wq, bq, q, Bc * Nc);
  gemm_xwT_kernel<<<dim3(4, 16), 256, 0, stream>>>(value_node, Wv, bv, v, Bc * Nc);
  // big k projection: [131072,256] @ Wk^T -> kbuf (edge region of d_out)
  gemm128_kernel<<<dim3(2, 1024), 256, 0, stream>>>(key_edge, Wk, bk, kbuf, Bc * Nc * Nc);
  // adjacency softmax
  adj_softmax_kernel<<<dim3(Bc * Nc), 128, 0, stream>>>(adj_matrix, mask, lam, adjs);
  // attention scores
  scores_kernel<<<dim3(Bc * Nc), 256, 0, stream>>>(kbuf, q, osc, isc);
  // softmaxes + message
  message_kernel<<<dim3(Bc * Hc * Nc), 128, 0, stream>>>(osc, isc, adjs, mask, msg);
  // node hidden + node projection
  node_hidden_kernel<<<dim3(Bc * Hc * 4), 256, 0, stream>>>(msg, v, nh);
  gemm_xwT_kernel<<<dim3(4, 16), 256, 0, stream>>>(nh, Wno, bno, node_out, Bc * Nc);
  // edge output, in place over kbuf
  edge_out_kernel<<<dim3(Bc * Nc * 2), 256, 0, stream>>>(kbuf, msg, Weo, beo);
}

// Round 4
// 542.310 us; speedup vs baseline: 1.8007x; 1.3554x over previous
//
#include <hip/hip_runtime.h>
#include <math.h>

#define Bc 8
#define Nc 128
#define Dc 256
#define Hc 8
#define DKc 32

typedef __attribute__((ext_vector_type(8))) short short8;
typedef __attribute__((ext_vector_type(4))) float floatx4;

__device__ __forceinline__ unsigned short f2bf(float f) {
  unsigned int u = __float_as_uint(f);
  u += 0x7FFFu + ((u >> 16) & 1u);   // RNE to bf16 (inputs are normal floats)
  return (unsigned short)(u >> 16);
}

// ---------------------------------------------------------------------------
// cast fp32 -> bf16 (for Wk, Weo; 65536 elements each)
// ---------------------------------------------------------------------------
__global__ __launch_bounds__(256) void cast_bf16_kernel(
    const float* __restrict__ src, unsigned short* __restrict__ dst, int n) {
  const int i = (blockIdx.x * 256 + threadIdx.x) * 4;
  if (i < n) {
    const float4 v = *(const float4*)&src[i];
    *(ushort4*)&dst[i] = make_ushort4(f2bf(v.x), f2bf(v.y), f2bf(v.z), f2bf(v.w));
  }
}

// ---------------------------------------------------------------------------
// Small GEMM (fp32): C[M,256] = X @ W^T + b. 64x64 tile. q/v/node projections.
// ---------------------------------------------------------------------------
__global__ __launch_bounds__(256) void gemm_xwT_kernel(
    const float* __restrict__ X, const float* __restrict__ W,
    const float* __restrict__ bias, float* __restrict__ C, int M) {
  __shared__ float As[64][17];
  __shared__ float Ws[64][17];
  const int t = threadIdx.x;
  const int tx = t & 15;
  const int ty = t >> 4;
  const size_t row0 = (size_t)blockIdx.y * 64;
  const int col0 = blockIdx.x * 64;
  const int lr = t >> 2;
  const int lc = (t & 3) * 4;

  float acc[4][4] = {};

  for (int kk = 0; kk < 256; kk += 16) {
    float4 av = *(const float4*)&X[(row0 + lr) * 256 + kk + lc];
    float4 wv = *(const float4*)&W[(size_t)(col0 + lr) * 256 + kk + lc];
    As[lr][lc] = av.x; As[lr][lc + 1] = av.y; As[lr][lc + 2] = av.z; As[lr][lc + 3] = av.w;
    Ws[lr][lc] = wv.x; Ws[lr][lc + 1] = wv.y; Ws[lr][lc + 2] = wv.z; Ws[lr][lc + 3] = wv.w;
    __syncthreads();
#pragma unroll
    for (int e = 0; e < 16; ++e) {
      float a[4], w[4];
#pragma unroll
      for (int r = 0; r < 4; ++r) a[r] = As[ty * 4 + r][e];
#pragma unroll
      for (int c = 0; c < 4; ++c) w[c] = Ws[tx * 4 + c][e];
#pragma unroll
      for (int r = 0; r < 4; ++r)
#pragma unroll
        for (int c = 0; c < 4; ++c) acc[r][c] = fmaf(a[r], w[c], acc[r][c]);
    }
    __syncthreads();
  }

  const float4 bv = *(const float4*)&bias[col0 + tx * 4];
#pragma unroll
  for (int r = 0; r < 4; ++r) {
    float4 o;
    o.x = acc[r][0] + bv.x;
    o.y = acc[r][1] + bv.y;
    o.z = acc[r][2] + bv.z;
    o.w = acc[r][3] + bv.w;
    *(float4*)&C[(row0 + ty * 4 + r) * 256 + col0 + tx * 4] = o;
  }
}

// ---------------------------------------------------------------------------
// MFMA k-projection: C[M,256] = bf16(X) @ bf16(Wk)^T + bk  (fp32 out)
// Block tile 128x128, BK=32, 256 threads (4 waves in 2x2), 4x4 MFMA tiles/wave.
// LDS row stride 40 bf16 (80 B: 16B-aligned frags, bank-spread).
// ---------------------------------------------------------------------------
__global__ __launch_bounds__(256) void kproj_mfma_kernel(
    const float* __restrict__ X, const unsigned short* __restrict__ Wbf,
    const float* __restrict__ bias, float* __restrict__ C) {
  __shared__ __align__(16) unsigned short As[128 * 40];
  __shared__ __align__(16) unsigned short Ws[128 * 40];
  const int t = threadIdx.x;
  const int l = t & 63;
  const int w = t >> 6;
  const int wm = w >> 1, wn = w & 1;
  const size_t row0 = (size_t)blockIdx.y * 128;
  const int col0 = blockIdx.x * 128;
  const int lr = l & 15;   // within-tile row (A) / col (B)
  const int lk = l >> 4;   // k-group (8 bf16 each)

  floatx4 acc[4][4] = {};

  for (int kk = 0; kk < 256; kk += 32) {
    float4 av[4];
#pragma unroll
    for (int p = 0; p < 4; ++p) {
      const int f = p * 256 + t;
      const int row = f >> 3, kc = (f & 7) * 4;
      av[p] = *(const float4*)&X[(row0 + row) * 256 + kk + kc];
    }
    uint4 wv[2];
#pragma unroll
    for (int p = 0; p < 2; ++p) {
      const int f = p * 256 + t;
      const int row = f >> 2, kc = (f & 3) * 8;
      wv[p] = *(const uint4*)&Wbf[(size_t)(col0 + row) * 256 + kk + kc];
    }
    __syncthreads();  // previous iteration's frag reads done
#pragma unroll
    for (int p = 0; p < 4; ++p) {
      const int f = p * 256 + t;
      const int row = f >> 3, kc = (f & 7) * 4;
      *(ushort4*)&As[row * 40 + kc] =
          make_ushort4(f2bf(av[p].x), f2bf(av[p].y), f2bf(av[p].z), f2bf(av[p].w));
    }
#pragma unroll
    for (int p = 0; p < 2; ++p) {
      const int f = p * 256 + t;
      const int row = f >> 2, kc = (f & 3) * 8;
      *(uint4*)&Ws[row * 40 + kc] = wv[p];
    }
    __syncthreads();
    short8 a[4], b[4];
#pragma unroll
    for (int i = 0; i < 4; ++i)
      a[i] = *(const short8*)&As[(wm * 64 + i * 16 + lr) * 40 + lk * 8];
#pragma unroll
    for (int j = 0; j < 4; ++j)
      b[j] = *(const short8*)&Ws[(wn * 64 + j * 16 + lr) * 40 + lk * 8];
#pragma unroll
    for (int i = 0; i < 4; ++i)
#pragma unroll
      for (int j = 0; j < 4; ++j)
        acc[i][j] = __builtin_amdgcn_mfma_f32_16x16x32_bf16(a[i], b[j], acc[i][j], 0, 0, 0);
  }

  float bj[4];
#pragma unroll
  for (int j = 0; j < 4; ++j) bj[j] = bias[col0 + wn * 64 + j * 16 + lr];
#pragma unroll
  for (int i = 0; i < 4; ++i)
#pragma unroll
    for (int r = 0; r < 4; ++r) {
      const size_t row = row0 + wm * 64 + i * 16 + lk * 4 + r;
#pragma unroll
      for (int j = 0; j < 4; ++j)
        C[row * 256 + col0 + wn * 64 + j * 16 + lr] = acc[i][j][r] + bj[j];
    }
}

// ---------------------------------------------------------------------------
// adjacency softmax (unchanged)
// ---------------------------------------------------------------------------
__global__ __launch_bounds__(128) void adj_softmax_kernel(
    const float* __restrict__ adj, const int* __restrict__ mask,
    const float* __restrict__ lam_p, float* __restrict__ adjs) {
  __shared__ float red[128];
  const int bi = blockIdx.x;
  const int b = bi >> 7;
  const int j = threadIdx.x;
  const float lam = lam_p[0];
  float x = (mask[b * 128 + j] != 0) ? (-lam * adj[(size_t)bi * 128 + j]) : -INFINITY;
  red[j] = x; __syncthreads();
  for (int s = 64; s > 0; s >>= 1) { if (j < s) red[j] = fmaxf(red[j], red[j + s]); __syncthreads(); }
  const float mx = red[0]; __syncthreads();
  const float e = expf(x - mx);
  red[j] = e; __syncthreads();
  for (int s = 64; s > 0; s >>= 1) { if (j < s) red[j] += red[j + s]; __syncthreads(); }
  const float z = red[0];
  adjs[(size_t)bi * 128 + j] = e / z;
}

// ---------------------------------------------------------------------------
// scores (unchanged)
// ---------------------------------------------------------------------------
__global__ __launch_bounds__(256) void scores_kernel(
    const float* __restrict__ kbuf, const float* __restrict__ q,
    float* __restrict__ osc, float* __restrict__ isc) {
  const int bm = blockIdx.x;
  const int b = bm >> 7;
  const int m = bm & 127;
  const int lane = threadIdx.x & 63;
  const int wave = threadIdx.x >> 6;
  const float inv_sqrt = 0.17677669529663687f;

  const float4 qm = *(const float4*)&q[((size_t)b * 128 + m) * 256 + lane * 4];

  for (int n = wave; n < 128; n += 4) {
    const float4 kr = *(const float4*)&kbuf[((size_t)bm * 128 + n) * 256 + lane * 4];
    const float4 qn = *(const float4*)&q[((size_t)b * 128 + n) * 256 + lane * 4];
    float po = kr.x * qm.x + kr.y * qm.y + kr.z * qm.z + kr.w * qm.w;
    float pi = kr.x * qn.x + kr.y * qn.y + kr.z * qn.z + kr.w * qn.w;
#pragma unroll
    for (int off = 1; off < 8; off <<= 1) {
      po += __shfl_xor(po, off, 64);
      pi += __shfl_xor(pi, off, 64);
    }
    if ((lane & 7) == 0) {
      const int h = lane >> 3;
      osc[(((size_t)(b * 8 + h) * 128 + m) * 128) + n] = po * inv_sqrt;
      isc[(((size_t)(b * 8 + h) * 128 + n) * 128) + m] = pi * inv_sqrt;
    }
  }
}

// ---------------------------------------------------------------------------
// message (unchanged)
// ---------------------------------------------------------------------------
__global__ __launch_bounds__(128) void message_kernel(
    const float* __restrict__ osc, const float* __restrict__ isc,
    const float* __restrict__ adjs, const int* __restrict__ mask,
    float* __restrict__ msg) {
  __shared__ float red[128];
  const int bhi = blockIdx.x;
  const int i = bhi & 127;
  const int b = bhi >> 10;
  const int j = threadIdx.x;
  const bool mj = mask[b * 128 + j] != 0;

  const float so = mj ? osc[(size_t)bhi * 128 + j] : -INFINITY;
  const float si = mj ? isc[(size_t)bhi * 128 + j] : -INFINITY;

  red[j] = so; __syncthreads();
  for (int s = 64; s > 0; s >>= 1) { if (j < s) red[j] = fmaxf(red[j], red[j + s]); __syncthreads(); }
  const float mo = red[0]; __syncthreads();
  const float eo = expf(so - mo);
  red[j] = eo; __syncthreads();
  for (int s = 64; s > 0; s >>= 1) { if (j < s) red[j] += red[j + s]; __syncthreads(); }
  const float zo = red[0]; __syncthreads();
  const float oa = eo / zo;

  red[j] = si; __syncthreads();
  for (int s = 64; s > 0; s >>= 1) { if (j < s) red[j] = fmaxf(red[j], red[j + s]); __syncthreads(); }
  const float mi = red[0]; __syncthreads();
  const float ei = expf(si - mi);
  red[j] = ei; __syncthreads();
  for (int s = 64; s > 0; s >>= 1) { if (j < s) red[j] += red[j + s]; __syncthreads(); }
  const float zi = red[0];
  const float ia = ei / zi;

  float val = oa + ia - ((i == j) ? oa : 0.0f);
  val *= adjs[((size_t)(b * 128 + i)) * 128 + j];
  msg[(size_t)bhi * 128 + j] = val;
}

// ---------------------------------------------------------------------------
// node_hidden (unchanged)
// ---------------------------------------------------------------------------
__global__ __launch_bounds__(256) void node_hidden_kernel(
    const float* __restrict__ msg, const float* __restrict__ v,
    float* __restrict__ nh) {
  __shared__ float Ms[32][129];
  __shared__ float Vs[128][33];
  const int blk = blockIdx.x;
  const int mblk = blk & 3;
  const int bh = blk >> 2;
  const int h = bh & 7;
  const int b = bh >> 3;
  const int t = threadIdx.x;

  {
    const int n = t & 127, r0 = t >> 7;
#pragma unroll
    for (int p = 0; p < 16; ++p) {
      const int r = r0 + p * 2;
      Ms[r][n] = msg[((size_t)bh * 128 + mblk * 32 + r) * 128 + n];
    }
  }
  {
    const int dk = t & 31, n0 = t >> 5;
#pragma unroll
    for (int p = 0; p < 16; ++p) {
      const int n = n0 + p * 8;
      Vs[n][dk] = v[((size_t)b * 128 + n) * 256 + h * 32 + dk];
    }
  }
  __syncthreads();

  const int dk = t & 31;
  const int mg = t >> 5;
  float acc[4] = {0.f, 0.f, 0.f, 0.f};
  for (int n = 0; n < 128; ++n) {
    const float vv = Vs[n][dk];
#pragma unroll
    for (int r = 0; r < 4; ++r) acc[r] = fmaf(Ms[mg + 8 * r][n], vv, acc[r]);
  }
#pragma unroll
  for (int r = 0; r < 4; ++r) {
    const int m = mblk * 32 + mg + 8 * r;
    nh[((size_t)b * 128 + m) * 256 + h * 32 + dk] = acc[r];
  }
}

// ---------------------------------------------------------------------------
// MFMA edge out, IN PLACE on kbuf: out = bf16(msg .* k) @ bf16(Weo)^T + beo.
// Block tile M=64 (rows fully owned: all 256 cols) x N=256; BK=32 = one head,
// so the msg scale is constant per K-chunk per row. 4 waves, each 64 cols.
// ---------------------------------------------------------------------------
__global__ __launch_bounds__(256) void edge_mfma_kernel(
    float* __restrict__ kio, const float* __restrict__ msg,
    const unsigned short* __restrict__ Wbf, const float* __restrict__ beo) {
  __shared__ __align__(16) unsigned short As[64 * 40];
  __shared__ __align__(16) unsigned short Ws[256 * 40];
  __shared__ float Msgs[64][8];
  const int nblk = blockIdx.x;          // 0..1
  const int bm = blockIdx.y;            // 0..1023
  const int b = bm >> 7;
  const int m = bm & 127;
  const int n0 = nblk * 64;
  const int t = threadIdx.x;
  const int l = t & 63;
  const int w = t >> 6;                 // wave -> col group of 64
  const int lr = l & 15;
  const int lk = l >> 4;

  // stage msg for these 64 rows x 8 heads
#pragma unroll
  for (int p = 0; p < 2; ++p) {
    const int idx = t + p * 256;
    const int r = idx >> 3, h = idx & 7;
    Msgs[r][h] = msg[(((size_t)(b * 8 + h) * 128 + m) * 128) + n0 + r];
  }
  __syncthreads();

  const size_t rowbase = ((size_t)bm * 128 + n0) * 256;
  floatx4 acc[4][4] = {};

  for (int kk = 0; kk < 256; kk += 32) {
    const int h = kk >> 5;
    float4 av[2];
    int arow[2];
#pragma unroll
    for (int p = 0; p < 2; ++p) {
      const int f = p * 256 + t;
      arow[p] = f >> 3;
      const int kc = (f & 7) * 4;
      av[p] = *(const float4*)&kio[rowbase + (size_t)arow[p] * 256 + kk + kc];
    }
    uint4 wv[4];
#pragma unroll
    for (int p = 0; p < 4; ++p) {
      const int f = p * 256 + t;
      const int row = f >> 2, kc = (f & 3) * 8;
      wv[p] = *(const uint4*)&Wbf[(size_t)row * 256 + kk + kc];
    }
    __syncthreads();  // previous iteration's frag reads done
#pragma unroll
    for (int p = 0; p < 2; ++p) {
      const int f = p * 256 + t;
      const int kc = (f & 7) * 4;
      const float sc = Msgs[arow[p]][h];
      *(ushort4*)&As[arow[p] * 40 + kc] =
          make_ushort4(f2bf(av[p].x * sc), f2bf(av[p].y * sc),
                       f2bf(av[p].z * sc), f2bf(av[p].w * sc));
    }
#pragma unroll
    for (int p = 0; p < 4; ++p) {
      const int f = p * 256 + t;
      const int row = f >> 2, kc = (f & 3) * 8;
      *(uint4*)&Ws[row * 40 + kc] = wv[p];
    }
    __syncthreads();
    short8 a[4], bfr[4];
#pragma unroll
    for (int i = 0; i < 4; ++i)
      a[i] = *(const short8*)&As[(i * 16 + lr) * 40 + lk * 8];
#pragma unroll
    for (int j = 0; j < 4; ++j)
      bfr[j] = *(const short8*)&Ws[(w * 64 + j * 16 + lr) * 40 + lk * 8];
#pragma unroll
    for (int i = 0; i < 4; ++i)
#pragma unroll
      for (int j = 0; j < 4; ++j)
        acc[i][j] = __builtin_amdgcn_mfma_f32_16x16x32_bf16(a[i], bfr[j], acc[i][j], 0, 0, 0);
  }

  float bj[4];
#pragma unroll
  for (int j = 0; j < 4; ++j) bj[j] = beo[w * 64 + j * 16 + lr];
  // in-place write: this block exclusively owns rows [rowbase, rowbase+64*256)
#pragma unroll
  for (int i = 0; i < 4; ++i)
#pragma unroll
    for (int r = 0; r < 4; ++r) {
      const size_t row = (size_t)(i * 16 + lk * 4 + r);
#pragma unroll
      for (int j = 0; j < 4; ++j)
        kio[rowbase + row * 256 + w * 64 + j * 16 + lr] = acc[i][j][r] + bj[j];
    }
}

// ---------------------------------------------------------------------------
extern "C" void kernel_launch(void* const* d_in, const int* in_sizes, int n_in,
                              void* d_out, int out_size, void* d_ws, size_t ws_size,
                              hipStream_t stream) {
  (void)in_sizes; (void)n_in; (void)out_size; (void)ws_size;
  const float* query_node = (const float*)d_in[0];
  const float* value_node = (const float*)d_in[1];
  const float* key_edge   = (const float*)d_in[2];
  const float* adj_matrix = (const float*)d_in[3];
  const int*   mask       = (const int*)d_in[4];
  const float* Wq  = (const float*)d_in[5];
  const float* bq  = (const float*)d_in[6];
  const float* Wk  = (const float*)d_in[7];
  const float* bk  = (const float*)d_in[8];
  const float* Wv  = (const float*)d_in[9];
  const float* bv  = (const float*)d_in[10];
  const float* Wno = (const float*)d_in[11];
  const float* bno = (const float*)d_in[12];
  const float* Weo = (const float*)d_in[13];
  const float* beo = (const float*)d_in[14];
  const float* lam = (const float*)d_in[15];

  float* out = (float*)d_out;
  float* node_out = out;                                  // [B,N,D]
  float* kbuf = out + (size_t)Bc * Nc * Dc;               // edge region doubles as k scratch

  float* ws = (float*)d_ws;
  float* q    = ws; ws += (size_t)Bc * Nc * Dc;
  float* v    = ws; ws += (size_t)Bc * Nc * Dc;
  float* adjs = ws; ws += (size_t)Bc * Nc * Nc;
  float* osc  = ws; ws += (size_t)Bc * Hc * Nc * Nc;
  float* isc  = ws; ws += (size_t)Bc * Hc * Nc * Nc;
  float* msg  = ws; ws += (size_t)Bc * Hc * Nc * Nc;
  float* nh   = ws; ws += (size_t)Bc * Nc * Dc;
  unsigned short* wkbf  = (unsigned short*)ws; ws += 32768;   // 65536 bf16
  unsigned short* weobf = (unsigned short*)ws; ws += 32768;   // 65536 bf16

  // pre-cast weights to bf16
  cast_bf16_kernel<<<dim3(64), 256, 0, stream>>>(Wk, wkbf, Dc * Dc);
  cast_bf16_kernel<<<dim3(64), 256, 0, stream>>>(Weo, weobf, Dc * Dc);
  // q, v projections (fp32, small)
  gemm_xwT_kernel<<<dim3(4, 16), 256, 0, stream>>>(query_node, Wq, bq, q, Bc * Nc);
  gemm_xwT_kernel<<<dim3(4, 16), 256, 0, stream>>>(value_node, Wv, bv, v, Bc * Nc);
  // big k projection via MFMA -> kbuf fp32 (edge region of d_out)
  kproj_mfma_kernel<<<dim3(2, 1024), 256, 0, stream>>>(key_edge, wkbf, bk, kbuf);
  // adjacency softmax
  adj_softmax_kernel<<<dim3(Bc * Nc), 128, 0, stream>>>(adj_matrix, mask, lam, adjs);
  // attention scores
  scores_kernel<<<dim3(Bc * Nc), 256, 0, stream>>>(kbuf, q, osc, isc);
  // softmaxes + message
  message_kernel<<<dim3(Bc * Hc * Nc), 128, 0, stream>>>(osc, isc, adjs, mask, msg);
  // node hidden + node projection (fp32)
  node_hidden_kernel<<<dim3(Bc * Hc * 4), 256, 0, stream>>>(msg, v, nh);
  gemm_xwT_kernel<<<dim3(4, 16), 256, 0, stream>>>(nh, Wno, bno, node_out, Bc * Nc);
  // edge output via MFMA, in place over kbuf
  edge_mfma_kernel<<<dim3(2, 1024), 256, 0, stream>>>(kbuf, msg, weobf, beo);
}